// Round 6
// baseline (460.174 us; speedup 1.0000x reference)
//
#include <hip/hip_runtime.h>
#include <math.h>

#define NH 16

typedef __bf16 bf16x8 __attribute__((ext_vector_type(8)));
typedef float f32x4 __attribute__((ext_vector_type(4)));

__device__ __forceinline__ unsigned short f2bf(float f) {
  unsigned u = __float_as_uint(f);
  u += 0x7fffu + ((u >> 16) & 1u);            // RNE (prep/epilogue paths only)
  return (unsigned short)(u >> 16);
}
__device__ __forceinline__ float bf2f(unsigned short h) {
  return __uint_as_float(((unsigned)h) << 16);
}
__device__ __forceinline__ float fast_tanh16(float x) {
  // tanh(8*x) for x = Q/8: 1 - 2/(e^{16x}+1)
  return 1.f - 2.f / (__expf(16.f * x) + 1.f);
}
__device__ __forceinline__ void gl_lds16(const void* g, void* l) {
  __builtin_amdgcn_global_load_lds((const __attribute__((address_space(1))) void*)g,
                                   (__attribute__((address_space(3))) void*)l, 16, 0, 0);
}
union Frag8 { bf16x8 v; unsigned short u[8]; };
union FragU { bf16x8 v; unsigned u[4]; };
union FragQ { bf16x8 v; unsigned long long q[2]; };

// ---------------------------------------------------------------------------
// prep_all: one launch for all input conversions.
//  bid <  4096 : x  f32 -> xh bf16
//  bid <  7168 : Wq|Wk|Wv f32 -> wcat3 bf16 [3072][1024]
//  else        : Wo f32 -> wocat [1024][2048] = [hi|lo]
// ---------------------------------------------------------------------------
__global__ __launch_bounds__(256) void prep_all(const float* __restrict__ x,
                                                const float* __restrict__ Wq,
                                                const float* __restrict__ Wk,
                                                const float* __restrict__ Wv,
                                                const float* __restrict__ Wo,
                                                unsigned short* __restrict__ xh,
                                                unsigned short* __restrict__ wcat3,
                                                unsigned short* __restrict__ wocat)
{
  const int bid = blockIdx.x, tid = threadIdx.x;
  if (bid < 4096) {
    int i = bid * 256 + tid;
    float4 v = *(const float4*)&x[(size_t)i*4];
    ushort4 o;
    o.x = f2bf(v.x); o.y = f2bf(v.y); o.z = f2bf(v.z); o.w = f2bf(v.w);
    *(ushort4*)&xh[(size_t)i*4] = o;
  } else if (bid < 7168) {
    int i = (bid - 4096) * 256 + tid;
    int sel = i >> 18, loc = i & 262143;
    const float* src = (sel == 0) ? Wq : (sel == 1) ? Wk : Wv;
    float4 v = *(const float4*)&src[(size_t)loc*4];
    ushort4 o;
    o.x = f2bf(v.x); o.y = f2bf(v.y); o.z = f2bf(v.z); o.w = f2bf(v.w);
    *(ushort4*)&wcat3[(size_t)i*4] = o;
  } else {
    int i = (bid - 7168) * 256 + tid;
    int r = i >> 8, c = i & 255;
    float4 v = *(const float4*)&Wo[(size_t)r*1024 + c*4];
    ushort4 hi, lo;
    hi.x = f2bf(v.x); lo.x = f2bf(v.x - bf2f(hi.x));
    hi.y = f2bf(v.y); lo.y = f2bf(v.y - bf2f(hi.y));
    hi.z = f2bf(v.z); lo.z = f2bf(v.z - bf2f(hi.z));
    hi.w = f2bf(v.w); lo.w = f2bf(v.w - bf2f(hi.w));
    *(ushort4*)&wocat[(size_t)r*2048 + c*4]        = hi;
    *(ushort4*)&wocat[(size_t)r*2048 + 1024 + c*4] = lo;
  }
}

// ---------------------------------------------------------------------------
// prep_jt: Jt[h][e][d] = bf16( lam * J[h][d][e] )  (transpose + lam fold)
// one block per head.
// ---------------------------------------------------------------------------
__global__ __launch_bounds__(256) void prep_jt(const float* __restrict__ J,
                                               const float* __restrict__ lam_p,
                                               unsigned short* __restrict__ Jt)
{
  __shared__ float T[64][65];
  const int h = blockIdx.x, tid = threadIdx.x;
  const float lam = lam_p[0];
#pragma unroll
  for (int c = 0; c < 4; ++c) {
    int i = tid + c*256;
    int d = i >> 4, e4 = i & 15;
    float4 v = *(const float4*)&J[(size_t)h*4096 + d*64 + e4*4];
    T[d][e4*4+0] = v.x; T[d][e4*4+1] = v.y; T[d][e4*4+2] = v.z; T[d][e4*4+3] = v.w;
  }
  __syncthreads();
  const int e = tid >> 2, d0 = (tid & 3) * 16;
#pragma unroll
  for (int j4 = 0; j4 < 4; ++j4) {
    ushort4 o;
    o.x = f2bf(lam * T[d0+j4*4+0][e]);
    o.y = f2bf(lam * T[d0+j4*4+1][e]);
    o.z = f2bf(lam * T[d0+j4*4+2][e]);
    o.w = f2bf(lam * T[d0+j4*4+3][e]);
    *(ushort4*)&Jt[((size_t)h*64 + e)*64 + d0 + j4*4] = o;
  }
}

// ---------------------------------------------------------------------------
// gemm_qkv: merged Q/K/V projection, 1-term bf16, 128x128 tile, BK=64.
// (unchanged from R5)
// ---------------------------------------------------------------------------
__global__ __launch_bounds__(256) void gemm_qkv(const unsigned short* __restrict__ A,
                                                const unsigned short* __restrict__ W,
                                                const float* __restrict__ bq,
                                                const float* __restrict__ bk,
                                                const float* __restrict__ bv,
                                                unsigned short* __restrict__ Qcat,
                                                unsigned short* __restrict__ Kcat,
                                                unsigned short* __restrict__ Vt)
{
  __shared__ unsigned short S[16384];
  const int tid = threadIdx.x, lane = tid & 63, wq = tid >> 6;
  const int l15 = lane & 15, lq = lane >> 4;
  const int n0 = blockIdx.x * 128, m0 = blockIdx.y * 128;
  const int wr = (wq & 1) * 64, wc = (wq >> 1) * 64;
  const int mode = n0 >> 10;

  f32x4 acc[4][4];
#pragma unroll
  for (int mb = 0; mb < 4; ++mb)
#pragma unroll
    for (int nb = 0; nb < 4; ++nb) { f32x4 z = {0.f,0.f,0.f,0.f}; acc[mb][nb] = z; }

  const unsigned short* mat = (wq < 2) ? A : W;
  const int rbase = (wq < 2) ? m0 : n0;
  unsigned short* lbase = S + (wq >> 1) * 8192;
  const int srow = lane >> 3, sslot = lane & 7;

  for (int k0 = 0; k0 < 1024; k0 += 64) {
    __syncthreads();
#pragma unroll
    for (int t = 0; t < 8; ++t) {
      int row = (wq & 1) * 64 + t*8 + srow;
      int chunk = sslot ^ (row & 7);
      gl_lds16(mat + (size_t)(rbase + row)*1024 + k0 + chunk*8,
               lbase + ((wq & 1) * 64 + t*8) * 64);
    }
    __syncthreads();
#pragma unroll
    for (int kk = 0; kk < 2; ++kk) {
      int c = kk*4 + lq;
      bf16x8 af[4], bf_[4];
#pragma unroll
      for (int mb = 0; mb < 4; ++mb) {
        int m = wr + mb*16 + l15;
        af[mb] = *(const bf16x8*)&S[m*64 + (c ^ (m & 7))*8];
      }
#pragma unroll
      for (int nb = 0; nb < 4; ++nb) {
        int n = wc + nb*16 + l15;
        bf_[nb] = *(const bf16x8*)&S[8192 + n*64 + (c ^ (n & 7))*8];
      }
#pragma unroll
      for (int mb = 0; mb < 4; ++mb)
#pragma unroll
        for (int nb = 0; nb < 4; ++nb)
          acc[mb][nb] = __builtin_amdgcn_mfma_f32_16x16x32_bf16(af[mb], bf_[nb], acc[mb][nb], 0,0,0);
    }
  }

  const float* bias = (mode == 0) ? bq : (mode == 1) ? bk : bv;
  float bvv[4];
#pragma unroll
  for (int nb = 0; nb < 4; ++nb) bvv[nb] = bias[((n0 & 1023) + wc + nb*16 + l15)];

  if (mode == 2) {
#pragma unroll
    for (int mb = 0; mb < 4; ++mb) {
      int mrow = m0 + wr + mb*16 + lq*4;
      int b = mrow >> 11, s0 = mrow & 2047;
#pragma unroll
      for (int nb = 0; nb < 4; ++nb) {
        int n = (n0 & 1023) + wc + nb*16 + l15;
        int h = n >> 6, d = n & 63;
        ushort4 o;
        o.x = f2bf(acc[mb][nb][0] + bvv[nb]);
        o.y = f2bf(acc[mb][nb][1] + bvv[nb]);
        o.z = f2bf(acc[mb][nb][2] + bvv[nb]);
        o.w = f2bf(acc[mb][nb][3] + bvv[nb]);
        *(ushort4*)&Vt[((size_t)(b*NH + h)*64 + d)*2048 + s0] = o;
      }
    }
    return;
  }

#pragma unroll
  for (int mb = 0; mb < 4; ++mb) {
#pragma unroll
    for (int r = 0; r < 4; ++r) {
      int m = m0 + wr + mb*16 + lq*4 + r;
      int b = m >> 11, s = m & 2047;
#pragma unroll
      for (int nb = 0; nb < 4; ++nb) {
        float v = acc[mb][nb][r] + bvv[nb];
        int n = (n0 & 1023) + wc + nb*16 + l15;
        int h = n >> 6, d = n & 63;
        size_t row = ((size_t)(b*NH + h)*2048 + s)*128;
        if (mode == 0) {
          Qcat[row + d] = f2bf(v * 0.125f);
        } else {
          Kcat[row + d]      = f2bf(v);
          Kcat[row + 64 + d] = f2bf(1.f - 2.f / (__expf(2.f*v) + 1.f));
        }
      }
    }
  }
}

// ---------------------------------------------------------------------------
// build_qj2: MFMA version. QJ[i][e] = sum_d tanh(8*q8[i][d]) * (lam*J[h][d][e])
// A-frags = tanh of Qcat lo (in-register), B-frags = Jt from global.
// Block: 128 rows of one bh (wave owns 32 rows). grid (16,32).
// ---------------------------------------------------------------------------
__global__ __launch_bounds__(256) void build_qj2(unsigned short* __restrict__ Qcat,
                                                 const unsigned short* __restrict__ Jt)
{
  const int tid = threadIdx.x, lane = tid & 63, wq = tid >> 6;
  const int l15 = lane & 15, lq = lane >> 4;
  const int bh = blockIdx.y, row0 = blockIdx.x * 128;
  const int h = bh & (NH-1);

  // B-frags: n = nb*16+l15 (e), k = kst*32+lq*8+j (d)
  bf16x8 jf[4][2];
#pragma unroll
  for (int nb = 0; nb < 4; ++nb)
#pragma unroll
    for (int kst = 0; kst < 2; ++kst)
      jf[nb][kst] = *(const bf16x8*)&Jt[((size_t)h*64 + nb*16 + l15)*64 + kst*32 + lq*8];

  // A-frags: m = mb*16+l15 (row), k = kst*32+lq*8+j; value = tanh(8*q8)
  Frag8 af[2][2];
#pragma unroll
  for (int mb = 0; mb < 2; ++mb) {
    const unsigned short* qp = Qcat + ((size_t)(bh*2048 + row0 + wq*32 + mb*16 + l15))*128 + lq*8;
#pragma unroll
    for (int kst = 0; kst < 2; ++kst) {
      Frag8 raw;
      raw.v = *(const bf16x8*)(qp + kst*32);
#pragma unroll
      for (int j = 0; j < 8; ++j) {
        float t = fast_tanh16(bf2f(raw.u[j]));
        af[mb][kst].u[j] = (unsigned short)(__float_as_uint(t) >> 16);  // trunc
      }
    }
  }

  f32x4 acc[2][4];
#pragma unroll
  for (int mb = 0; mb < 2; ++mb)
#pragma unroll
    for (int nb = 0; nb < 4; ++nb) { f32x4 z = {0.f,0.f,0.f,0.f}; acc[mb][nb] = z; }
#pragma unroll
  for (int kst = 0; kst < 2; ++kst)
#pragma unroll
    for (int mb = 0; mb < 2; ++mb)
#pragma unroll
      for (int nb = 0; nb < 4; ++nb)
        acc[mb][nb] = __builtin_amdgcn_mfma_f32_16x16x32_bf16(af[mb][kst].v, jf[nb][kst], acc[mb][nb], 0,0,0);

  // C: row = row0+wq*32+mb*16+lq*4+r, col(e) = nb*16+l15 -> Qcat hi half
#pragma unroll
  for (int mb = 0; mb < 2; ++mb)
#pragma unroll
    for (int r = 0; r < 4; ++r) {
      size_t rowb = ((size_t)(bh*2048 + row0 + wq*32 + mb*16 + lq*4 + r))*128 + 64;
#pragma unroll
      for (int nb = 0; nb < 4; ++nb)
        Qcat[rowb + nb*16 + l15] = f2bf(acc[mb][nb][r]);
    }
}

// ---------------------------------------------------------------------------
// flash5: S^T MFMA flash, split-K4, atomic-accumulate epilogue.
// Block: BM=128 qrows (wave owns 32), 512 keys (8 jt of 64). grid 2048.
// Softmax: no-max streaming (|s|<~6), p TRUNCATED to bf16 via v_perm (bias
// cancels: l sums the same truncated p). LDS 24KB -> 6 blocks/CU.
// ---------------------------------------------------------------------------
__global__ __launch_bounds__(256, 6) void flash5(
    const unsigned short* __restrict__ Qcat, const unsigned short* __restrict__ Kcat,
    const unsigned short* __restrict__ Vt, float* __restrict__ Oacc,
    float* __restrict__ lacc)
{
  __shared__ unsigned short Ks[64*128];
  __shared__ unsigned short Vs[64*64];
  const int tid = threadIdx.x, lane = tid & 63, wq = tid >> 6;
  const int l15 = lane & 15, lq = lane >> 4;
  const int bid = blockIdx.x;
  const int bh = ((bid >> 9) << 3) | (bid & 7);       // XCD-friendly
  const int inner = (bid >> 3) & 63;
  const int row0 = (inner & 15) * 128;
  const int ks = inner >> 4;                           // 0..3, 512 keys each

  Frag8 qf[2][4];
#pragma unroll
  for (int nb = 0; nb < 2; ++nb) {
    const unsigned short* qp = Qcat + ((size_t)(bh*2048 + row0 + wq*32 + nb*16 + l15))*128 + lq*8;
#pragma unroll
    for (int kst = 0; kst < 4; ++kst)
      qf[nb][kst].v = *(const bf16x8*)(qp + kst*32);
  }

  f32x4 o[4][2];
  float lp[2] = {0.f, 0.f};
#pragma unroll
  for (int db = 0; db < 4; ++db)
#pragma unroll
    for (int nb = 0; nb < 2; ++nb) { f32x4 z = {0.f,0.f,0.f,0.f}; o[db][nb] = z; }

  const unsigned short* kg0 = Kcat + ((size_t)(bh*2048 + ks*512))*128;
  const unsigned short* vg  = Vt + (size_t)bh*64*2048;
  const int koff0 = ks*512;

  for (int jt = 0; jt < 8; ++jt) {
    __syncthreads();
#pragma unroll
    for (int t = 0; t < 4; ++t) {
      int g = (wq*4 + t)*4 + (lane >> 4);
      int slot = lane & 15;
      int chunk = (slot & 8) | ((slot ^ g) & 7);
      gl_lds16(kg0 + (size_t)(jt*64 + g)*128 + chunk*8, Ks + (wq*4 + t)*512);
    }
#pragma unroll
    for (int t = 0; t < 2; ++t) {
      int rv = (wq*2 + t)*8 + (lane >> 3);
      int chunk = (lane & 7) ^ (rv & 7);
      gl_lds16(vg + (size_t)rv*2048 + koff0 + jt*64 + chunk*8, Vs + (wq*2 + t)*512);
    }
    __syncthreads();

    unsigned P2[2][4][2];
#pragma unroll
    for (int kb = 0; kb < 4; ++kb) {
      bf16x8 af[4];
#pragma unroll
      for (int kst = 0; kst < 4; ++kst) {
        int key = kb*16 + l15;
        int c = kst*4 + lq;
        int slot = (c & 8) | ((c ^ key) & 7);
        af[kst] = *(const bf16x8*)&Ks[key*128 + slot*8];
      }
      f32x4 s[2];
      { f32x4 z = {0.f,0.f,0.f,0.f}; s[0] = z; s[1] = z; }
#pragma unroll
      for (int kst = 0; kst < 4; ++kst) {
        s[0] = __builtin_amdgcn_mfma_f32_16x16x32_bf16(af[kst], qf[0][kst].v, s[0], 0,0,0);
        s[1] = __builtin_amdgcn_mfma_f32_16x16x32_bf16(af[kst], qf[1][kst].v, s[1], 0,0,0);
      }
#pragma unroll
      for (int nb = 0; nb < 2; ++nb) {
        float e0 = __expf(s[nb][0]), e1 = __expf(s[nb][1]);
        float e2 = __expf(s[nb][2]), e3 = __expf(s[nb][3]);
        unsigned pk0 = __builtin_amdgcn_perm(__float_as_uint(e1), __float_as_uint(e0), 0x07060302u);
        unsigned pk1 = __builtin_amdgcn_perm(__float_as_uint(e3), __float_as_uint(e2), 0x07060302u);
        lp[nb] += __uint_as_float(pk0 << 16) + __uint_as_float(pk0 & 0xffff0000u)
                + __uint_as_float(pk1 << 16) + __uint_as_float(pk1 & 0xffff0000u);
        P2[nb][kb][0] = pk0;
        P2[nb][kb][1] = pk1;
      }
    }

    // PV: O^T += V^T . P^T
#pragma unroll
    for (int t = 0; t < 2; ++t) {
      FragU bfr[2];
#pragma unroll
      for (int nb = 0; nb < 2; ++nb) {
        bfr[nb].u[0] = P2[nb][2*t][0];
        bfr[nb].u[1] = P2[nb][2*t][1];
        bfr[nb].u[2] = P2[nb][2*t+1][0];
        bfr[nb].u[3] = P2[nb][2*t+1][1];
      }
      const int c0 = 4*t + (lq >> 1);
      const int woff = 4*(lq & 1);
#pragma unroll
      for (int db = 0; db < 4; ++db) {
        int d = db*16 + l15;
        FragQ va;
        va.q[0] = *(const unsigned long long*)&Vs[d*64 + ((c0     ^ (d & 7))*8) + woff];
        va.q[1] = *(const unsigned long long*)&Vs[d*64 + (((c0+2) ^ (d & 7))*8) + woff];
        o[db][0] = __builtin_amdgcn_mfma_f32_16x16x32_bf16(va.v, bfr[0].v, o[db][0], 0,0,0);
        o[db][1] = __builtin_amdgcn_mfma_f32_16x16x32_bf16(va.v, bfr[1].v, o[db][1], 0,0,0);
      }
    }
  }

  // epilogue: atomic accumulate partials
#pragma unroll
  for (int nb = 0; nb < 2; ++nb) {
    float rs = lp[nb];
    rs += __shfl_xor(rs, 16, 64);
    rs += __shfl_xor(rs, 32, 64);
    int qrow = row0 + wq*32 + nb*16 + l15;
    if (lq == 0) atomicAdd(&lacc[(size_t)bh*2048 + qrow], rs);
#pragma unroll
    for (int db = 0; db < 4; ++db)
#pragma unroll
      for (int r = 0; r < 4; ++r) {
        int d = db*16 + lq*4 + r;
        atomicAdd(&Oacc[(size_t)(bh*64 + d)*2048 + qrow], o[db][nb][r]);
      }
  }
}

// ---------------------------------------------------------------------------
// combine2: attcat[b,s,h*64+d](hi|lo) = Oacc[bh][d][s] / lacc[bh][s]
// ---------------------------------------------------------------------------
__global__ __launch_bounds__(256) void combine2(const float* __restrict__ Oacc,
                                                const float* __restrict__ lacc,
                                                unsigned short* __restrict__ attcat)
{
  __shared__ float Ts[64*68];
  __shared__ float Ls[64];
  const int tid = threadIdx.x;
  const int bh = blockIdx.y, s0 = blockIdx.x * 64;
  const int b = bh >> 4, h = bh & (NH-1);
#pragma unroll
  for (int c = 0; c < 4; ++c) {
    int fid = tid + c*256;
    int d = fid >> 4, s4 = fid & 15;
    float4 a = *(const float4*)&Oacc[((size_t)(bh*64 + d))*2048 + s0 + s4*4];
    Ts[(s4*4+0)*68 + d] = a.x;
    Ts[(s4*4+1)*68 + d] = a.y;
    Ts[(s4*4+2)*68 + d] = a.z;
    Ts[(s4*4+3)*68 + d] = a.w;
  }
  if (tid < 64) Ls[tid] = lacc[(size_t)bh*2048 + s0 + tid];
  __syncthreads();
  const int sl = tid >> 2, d0 = (tid & 3) * 16;
  const float inv = 1.f / Ls[sl];
  const size_t rb = ((size_t)(b*2048 + s0 + sl))*2048 + h*64;
#pragma unroll
  for (int j4 = 0; j4 < 4; ++j4) {
    float4 t = *(const float4*)&Ts[sl*68 + d0 + j4*4];
    float v0 = t.x*inv, v1 = t.y*inv, v2 = t.z*inv, v3 = t.w*inv;
    ushort4 hi, lo;
    hi.x = f2bf(v0); lo.x = f2bf(v0 - bf2f(hi.x));
    hi.y = f2bf(v1); lo.y = f2bf(v1 - bf2f(hi.y));
    hi.z = f2bf(v2); lo.z = f2bf(v2 - bf2f(hi.z));
    hi.w = f2bf(v3); lo.w = f2bf(v3 - bf2f(hi.w));
    *(ushort4*)&attcat[rb + d0 + j4*4]        = hi;
    *(ushort4*)&attcat[rb + 1024 + d0 + j4*4] = lo;
  }
}

// ---------------------------------------------------------------------------
// gemm3: out = attn@Wo^T + bo, split-bf16 3-term (unchanged).
// ---------------------------------------------------------------------------
__global__ __launch_bounds__(256) void gemm3(const unsigned short* __restrict__ A,
                                             const unsigned short* __restrict__ W,
                                             const float* __restrict__ bias,
                                             float* __restrict__ out)
{
  __shared__ unsigned short S[16384];
  const int tid = threadIdx.x, lane = tid & 63, wq = tid >> 6;
  const int l15 = lane & 15, lq = lane >> 4;
  const int n0 = blockIdx.x * 64, m0 = blockIdx.y * 64;
  const int wr = (wq & 1) * 32, wc = (wq >> 1) * 32;

  f32x4 acc[2][2];
#pragma unroll
  for (int mb = 0; mb < 2; ++mb)
#pragma unroll
    for (int nb = 0; nb < 2; ++nb) { f32x4 z = {0.f,0.f,0.f,0.f}; acc[mb][nb] = z; }

  const unsigned short* mat = (wq < 2) ? A : W;
  const int rbase = (wq < 2) ? m0 : n0;
  const int koffadd = (wq & 1) * 1024;
  unsigned short* lbase = S + wq * 4096;
  const int srow = lane >> 3, sslot = lane & 7;

  for (int k0 = 0; k0 < 1024; k0 += 64) {
    __syncthreads();
#pragma unroll
    for (int t = 0; t < 8; ++t) {
      int row = t*8 + srow;
      int chunk = sslot ^ (row & 7);
      gl_lds16(mat + (size_t)(rbase + row)*2048 + koffadd + k0 + chunk*8, lbase + t*512);
    }
    __syncthreads();
#pragma unroll
    for (int kk = 0; kk < 2; ++kk) {
      int c = kk*4 + lq;
      bf16x8 ah[2], al[2], bh_[2], bl_[2];
#pragma unroll
      for (int mb = 0; mb < 2; ++mb) {
        int m = wr + mb*16 + l15;
        int so = (c ^ (m & 7))*8;
        ah[mb] = *(const bf16x8*)&S[m*64 + so];
        al[mb] = *(const bf16x8*)&S[4096 + m*64 + so];
      }
#pragma unroll
      for (int nb = 0; nb < 2; ++nb) {
        int n = wc + nb*16 + l15;
        int so = (c ^ (n & 7))*8;
        bh_[nb] = *(const bf16x8*)&S[8192  + n*64 + so];
        bl_[nb] = *(const bf16x8*)&S[12288 + n*64 + so];
      }
#pragma unroll
      for (int mb = 0; mb < 2; ++mb)
#pragma unroll
        for (int nb = 0; nb < 2; ++nb) {
          acc[mb][nb] = __builtin_amdgcn_mfma_f32_16x16x32_bf16(ah[mb], bh_[nb], acc[mb][nb], 0,0,0);
          acc[mb][nb] = __builtin_amdgcn_mfma_f32_16x16x32_bf16(al[mb], bh_[nb], acc[mb][nb], 0,0,0);
          acc[mb][nb] = __builtin_amdgcn_mfma_f32_16x16x32_bf16(ah[mb], bl_[nb], acc[mb][nb], 0,0,0);
        }
    }
  }

  float bvv[2];
#pragma unroll
  for (int nb = 0; nb < 2; ++nb) bvv[nb] = bias[n0 + wc + nb*16 + l15];
#pragma unroll
  for (int mb = 0; mb < 2; ++mb)
#pragma unroll
    for (int r = 0; r < 4; ++r) {
      int m = m0 + wr + mb*16 + lq*4 + r;
#pragma unroll
      for (int nb = 0; nb < 2; ++nb) {
        int n = n0 + wc + nb*16 + l15;
        out[(size_t)m*1024 + n] = acc[mb][nb][r] + bvv[nb];
      }
    }
}

// ---------------------------------------------------------------------------
extern "C" void kernel_launch(void* const* d_in, const int* in_sizes, int n_in,
                              void* d_out, int out_size, void* d_ws, size_t ws_size,
                              hipStream_t stream)
{
  const float* x   = (const float*)d_in[0];
  const float* Wq  = (const float*)d_in[1];
  const float* bq  = (const float*)d_in[2];
  const float* Wk  = (const float*)d_in[3];
  const float* bk  = (const float*)d_in[4];
  const float* Wv  = (const float*)d_in[5];
  const float* bv  = (const float*)d_in[6];
  const float* Wo  = (const float*)d_in[7];
  const float* bo  = (const float*)d_in[8];
  const float* J   = (const float*)d_in[9];
  const float* lam = (const float*)d_in[10];

  // ws layout (~95 MB)
  char* p = (char*)d_ws;
  unsigned short* xh     = (unsigned short*)p;  p += (size_t)4096*1024*2;    //  8.4M
  unsigned short* Qcat   = (unsigned short*)p;  p += (size_t)65536*128*2;    // 16.8M
  unsigned short* Kcat   = (unsigned short*)p;  p += (size_t)65536*128*2;    // 16.8M
  unsigned short* Vt     = (unsigned short*)p;  p += (size_t)32*64*2048*2;   //  8.4M
  unsigned short* wcat3  = (unsigned short*)p;  p += (size_t)3072*1024*2;    //  6.3M
  unsigned short* wocat  = (unsigned short*)p;  p += (size_t)1024*2048*2;    //  4.2M
  unsigned short* attcat = (unsigned short*)p;  p += (size_t)4096*2048*2;    // 16.8M
  unsigned short* Jt     = (unsigned short*)p;  p += (size_t)16*64*64*2;     //  0.13M
  float*          Oacc   = (float*)p;           p += (size_t)32*64*2048*4;   // 16.8M
  float*          lacc   = (float*)p;           p += (size_t)32*2048*4;      //  0.26M
  float* out = (float*)d_out;

  dim3 blk(256);

  hipMemsetAsync(Oacc, 0, (size_t)(32*64*2048 + 32*2048)*4, stream);  // Oacc+lacc (contiguous)
  prep_all<<<dim3(8192), blk, 0, stream>>>(x, Wq, Wk, Wv, Wo, xh, wcat3, wocat);
  prep_jt<<<dim3(16), blk, 0, stream>>>(J, lam, Jt);
  gemm_qkv<<<dim3(24, 32), blk, 0, stream>>>(xh, wcat3, bq, bk, bv, Qcat, Kcat, Vt);
  build_qj2<<<dim3(16, 32), blk, 0, stream>>>(Qcat, Jt);
  flash5<<<dim3(2048), blk, 0, stream>>>(Qcat, Kcat, Vt, Oacc, lacc);
  combine2<<<dim3(32, 32), blk, 0, stream>>>(Oacc, lacc, attcat);
  gemm3<<<dim3(16, 64), blk, 0, stream>>>(attcat, wocat, bo, out);
}

// Round 7
// 444.337 us; speedup vs baseline: 1.0356x; 1.0356x over previous
//
#include <hip/hip_runtime.h>
#include <math.h>

#define NH 16

typedef __bf16 bf16x8 __attribute__((ext_vector_type(8)));
typedef float f32x4 __attribute__((ext_vector_type(4)));

__device__ __forceinline__ unsigned short f2bf(float f) {
  unsigned u = __float_as_uint(f);
  u += 0x7fffu + ((u >> 16) & 1u);            // RNE (prep/epilogue paths only)
  return (unsigned short)(u >> 16);
}
__device__ __forceinline__ float bf2f(unsigned short h) {
  return __uint_as_float(((unsigned)h) << 16);
}
__device__ __forceinline__ float fast_tanh16(float x) {
  // tanh(8*x) for x = Q/8: 1 - 2/(e^{16x}+1)
  return 1.f - 2.f / (__expf(16.f * x) + 1.f);
}
__device__ __forceinline__ void gl_lds16(const void* g, void* l) {
  __builtin_amdgcn_global_load_lds((const __attribute__((address_space(1))) void*)g,
                                   (__attribute__((address_space(3))) void*)l, 16, 0, 0);
}
union Frag8 { bf16x8 v; unsigned short u[8]; };
union FragU { bf16x8 v; unsigned u[4]; };
union FragQ { bf16x8 v; unsigned long long q[2]; };

// ---------------------------------------------------------------------------
// prep_all: one launch for all input conversions.
// ---------------------------------------------------------------------------
__global__ __launch_bounds__(256) void prep_all(const float* __restrict__ x,
                                                const float* __restrict__ Wq,
                                                const float* __restrict__ Wk,
                                                const float* __restrict__ Wv,
                                                const float* __restrict__ Wo,
                                                unsigned short* __restrict__ xh,
                                                unsigned short* __restrict__ wcat3,
                                                unsigned short* __restrict__ wocat)
{
  const int bid = blockIdx.x, tid = threadIdx.x;
  if (bid < 4096) {
    int i = bid * 256 + tid;
    float4 v = *(const float4*)&x[(size_t)i*4];
    ushort4 o;
    o.x = f2bf(v.x); o.y = f2bf(v.y); o.z = f2bf(v.z); o.w = f2bf(v.w);
    *(ushort4*)&xh[(size_t)i*4] = o;
  } else if (bid < 7168) {
    int i = (bid - 4096) * 256 + tid;
    int sel = i >> 18, loc = i & 262143;
    const float* src = (sel == 0) ? Wq : (sel == 1) ? Wk : Wv;
    float4 v = *(const float4*)&src[(size_t)loc*4];
    ushort4 o;
    o.x = f2bf(v.x); o.y = f2bf(v.y); o.z = f2bf(v.z); o.w = f2bf(v.w);
    *(ushort4*)&wcat3[(size_t)i*4] = o;
  } else {
    int i = (bid - 7168) * 256 + tid;
    int r = i >> 8, c = i & 255;
    float4 v = *(const float4*)&Wo[(size_t)r*1024 + c*4];
    ushort4 hi, lo;
    hi.x = f2bf(v.x); lo.x = f2bf(v.x - bf2f(hi.x));
    hi.y = f2bf(v.y); lo.y = f2bf(v.y - bf2f(hi.y));
    hi.z = f2bf(v.z); lo.z = f2bf(v.z - bf2f(hi.z));
    hi.w = f2bf(v.w); lo.w = f2bf(v.w - bf2f(hi.w));
    *(ushort4*)&wocat[(size_t)r*2048 + c*4]        = hi;
    *(ushort4*)&wocat[(size_t)r*2048 + 1024 + c*4] = lo;
  }
}

// ---------------------------------------------------------------------------
// prep_jt: Jt[h][e][d] = bf16( lam * J[h][d][e] )
// ---------------------------------------------------------------------------
__global__ __launch_bounds__(256) void prep_jt(const float* __restrict__ J,
                                               const float* __restrict__ lam_p,
                                               unsigned short* __restrict__ Jt)
{
  __shared__ float T[64][65];
  const int h = blockIdx.x, tid = threadIdx.x;
  const float lam = lam_p[0];
#pragma unroll
  for (int c = 0; c < 4; ++c) {
    int i = tid + c*256;
    int d = i >> 4, e4 = i & 15;
    float4 v = *(const float4*)&J[(size_t)h*4096 + d*64 + e4*4];
    T[d][e4*4+0] = v.x; T[d][e4*4+1] = v.y; T[d][e4*4+2] = v.z; T[d][e4*4+3] = v.w;
  }
  __syncthreads();
  const int e = tid >> 2, d0 = (tid & 3) * 16;
#pragma unroll
  for (int j4 = 0; j4 < 4; ++j4) {
    ushort4 o;
    o.x = f2bf(lam * T[d0+j4*4+0][e]);
    o.y = f2bf(lam * T[d0+j4*4+1][e]);
    o.z = f2bf(lam * T[d0+j4*4+2][e]);
    o.w = f2bf(lam * T[d0+j4*4+3][e]);
    *(ushort4*)&Jt[((size_t)h*64 + e)*64 + d0 + j4*4] = o;
  }
}

// ---------------------------------------------------------------------------
// gemm_qkv: merged Q/K/V projection, 1-term bf16, 128x128 tile, BK=64.
// ---------------------------------------------------------------------------
__global__ __launch_bounds__(256) void gemm_qkv(const unsigned short* __restrict__ A,
                                                const unsigned short* __restrict__ W,
                                                const float* __restrict__ bq,
                                                const float* __restrict__ bk,
                                                const float* __restrict__ bv,
                                                unsigned short* __restrict__ Qcat,
                                                unsigned short* __restrict__ Kcat,
                                                unsigned short* __restrict__ Vt)
{
  __shared__ unsigned short S[16384];
  const int tid = threadIdx.x, lane = tid & 63, wq = tid >> 6;
  const int l15 = lane & 15, lq = lane >> 4;
  const int n0 = blockIdx.x * 128, m0 = blockIdx.y * 128;
  const int wr = (wq & 1) * 64, wc = (wq >> 1) * 64;
  const int mode = n0 >> 10;

  f32x4 acc[4][4];
#pragma unroll
  for (int mb = 0; mb < 4; ++mb)
#pragma unroll
    for (int nb = 0; nb < 4; ++nb) { f32x4 z = {0.f,0.f,0.f,0.f}; acc[mb][nb] = z; }

  const unsigned short* mat = (wq < 2) ? A : W;
  const int rbase = (wq < 2) ? m0 : n0;
  unsigned short* lbase = S + (wq >> 1) * 8192;
  const int srow = lane >> 3, sslot = lane & 7;

  for (int k0 = 0; k0 < 1024; k0 += 64) {
    __syncthreads();
#pragma unroll
    for (int t = 0; t < 8; ++t) {
      int row = (wq & 1) * 64 + t*8 + srow;
      int chunk = sslot ^ (row & 7);
      gl_lds16(mat + (size_t)(rbase + row)*1024 + k0 + chunk*8,
               lbase + ((wq & 1) * 64 + t*8) * 64);
    }
    __syncthreads();
#pragma unroll
    for (int kk = 0; kk < 2; ++kk) {
      int c = kk*4 + lq;
      bf16x8 af[4], bf_[4];
#pragma unroll
      for (int mb = 0; mb < 4; ++mb) {
        int m = wr + mb*16 + l15;
        af[mb] = *(const bf16x8*)&S[m*64 + (c ^ (m & 7))*8];
      }
#pragma unroll
      for (int nb = 0; nb < 4; ++nb) {
        int n = wc + nb*16 + l15;
        bf_[nb] = *(const bf16x8*)&S[8192 + n*64 + (c ^ (n & 7))*8];
      }
#pragma unroll
      for (int mb = 0; mb < 4; ++mb)
#pragma unroll
        for (int nb = 0; nb < 4; ++nb)
          acc[mb][nb] = __builtin_amdgcn_mfma_f32_16x16x32_bf16(af[mb], bf_[nb], acc[mb][nb], 0,0,0);
    }
  }

  const float* bias = (mode == 0) ? bq : (mode == 1) ? bk : bv;
  float bvv[4];
#pragma unroll
  for (int nb = 0; nb < 4; ++nb) bvv[nb] = bias[((n0 & 1023) + wc + nb*16 + l15)];

  if (mode == 2) {
#pragma unroll
    for (int mb = 0; mb < 4; ++mb) {
      int mrow = m0 + wr + mb*16 + lq*4;
      int b = mrow >> 11, s0 = mrow & 2047;
#pragma unroll
      for (int nb = 0; nb < 4; ++nb) {
        int n = (n0 & 1023) + wc + nb*16 + l15;
        int h = n >> 6, d = n & 63;
        ushort4 o;
        o.x = f2bf(acc[mb][nb][0] + bvv[nb]);
        o.y = f2bf(acc[mb][nb][1] + bvv[nb]);
        o.z = f2bf(acc[mb][nb][2] + bvv[nb]);
        o.w = f2bf(acc[mb][nb][3] + bvv[nb]);
        *(ushort4*)&Vt[((size_t)(b*NH + h)*64 + d)*2048 + s0] = o;
      }
    }
    return;
  }

#pragma unroll
  for (int mb = 0; mb < 4; ++mb) {
#pragma unroll
    for (int r = 0; r < 4; ++r) {
      int m = m0 + wr + mb*16 + lq*4 + r;
      int b = m >> 11, s = m & 2047;
#pragma unroll
      for (int nb = 0; nb < 4; ++nb) {
        float v = acc[mb][nb][r] + bvv[nb];
        int n = (n0 & 1023) + wc + nb*16 + l15;
        int h = n >> 6, d = n & 63;
        size_t row = ((size_t)(b*NH + h)*2048 + s)*128;
        if (mode == 0) {
          Qcat[row + d] = f2bf(v * 0.125f);
        } else {
          Kcat[row + d]      = f2bf(v);
          Kcat[row + 64 + d] = f2bf(1.f - 2.f / (__expf(2.f*v) + 1.f));
        }
      }
    }
  }
}

// ---------------------------------------------------------------------------
// build_qj2: MFMA. Qcat hi = bf16( sum_d tanh(8*q8[d]) * (lam*J[h][d][e]) )
// ---------------------------------------------------------------------------
__global__ __launch_bounds__(256) void build_qj2(unsigned short* __restrict__ Qcat,
                                                 const unsigned short* __restrict__ Jt)
{
  const int tid = threadIdx.x, lane = tid & 63, wq = tid >> 6;
  const int l15 = lane & 15, lq = lane >> 4;
  const int bh = blockIdx.y, row0 = blockIdx.x * 128;
  const int h = bh & (NH-1);

  bf16x8 jf[4][2];
#pragma unroll
  for (int nb = 0; nb < 4; ++nb)
#pragma unroll
    for (int kst = 0; kst < 2; ++kst)
      jf[nb][kst] = *(const bf16x8*)&Jt[((size_t)h*64 + nb*16 + l15)*64 + kst*32 + lq*8];

  Frag8 af[2][2];
#pragma unroll
  for (int mb = 0; mb < 2; ++mb) {
    const unsigned short* qp = Qcat + ((size_t)(bh*2048 + row0 + wq*32 + mb*16 + l15))*128 + lq*8;
#pragma unroll
    for (int kst = 0; kst < 2; ++kst) {
      Frag8 raw;
      raw.v = *(const bf16x8*)(qp + kst*32);
#pragma unroll
      for (int j = 0; j < 8; ++j) {
        float t = fast_tanh16(bf2f(raw.u[j]));
        af[mb][kst].u[j] = (unsigned short)(__float_as_uint(t) >> 16);  // trunc
      }
    }
  }

  f32x4 acc[2][4];
#pragma unroll
  for (int mb = 0; mb < 2; ++mb)
#pragma unroll
    for (int nb = 0; nb < 4; ++nb) { f32x4 z = {0.f,0.f,0.f,0.f}; acc[mb][nb] = z; }
#pragma unroll
  for (int kst = 0; kst < 2; ++kst)
#pragma unroll
    for (int mb = 0; mb < 2; ++mb)
#pragma unroll
      for (int nb = 0; nb < 4; ++nb)
        acc[mb][nb] = __builtin_amdgcn_mfma_f32_16x16x32_bf16(af[mb][kst].v, jf[nb][kst], acc[mb][nb], 0,0,0);

#pragma unroll
  for (int mb = 0; mb < 2; ++mb)
#pragma unroll
    for (int r = 0; r < 4; ++r) {
      size_t rowb = ((size_t)(bh*2048 + row0 + wq*32 + mb*16 + lq*4 + r))*128 + 64;
#pragma unroll
      for (int nb = 0; nb < 4; ++nb)
        Qcat[rowb + nb*16 + l15] = f2bf(acc[mb][nb][r]);
    }
}

// ---------------------------------------------------------------------------
// flash6: S^T MFMA flash, split-K3 (explicit f32 partials — NO atomics; R6
// showed cross-XCD atomic accumulate costs ~20x traffic). grid 1536 =
// 6 blocks/CU (matches the 24KB-LDS residency cap). Lean perm-trunc softmax.
// Slices: ks=0,1 -> 11 jt; ks=2 -> 10 jt (64 keys each).
// ---------------------------------------------------------------------------
__global__ __launch_bounds__(256, 6) void flash6(
    const unsigned short* __restrict__ Qcat, const unsigned short* __restrict__ Kcat,
    const unsigned short* __restrict__ Vt, float* __restrict__ OP0,
    float* __restrict__ OP1, float* __restrict__ OP2, float* __restrict__ lpart)
{
  __shared__ unsigned short Ks[64*128];
  __shared__ unsigned short Vs[64*64];
  const int tid = threadIdx.x, lane = tid & 63, wq = tid >> 6;
  const int l15 = lane & 15, lq = lane >> 4;
  const int bid = blockIdx.x;
  // bid = xcd + 8*(bhi + 4*inner): same bh -> same XCD L2
  const int bh = (((bid >> 3) & 3) << 3) | (bid & 7);
  const int inner = bid >> 5;                  // 0..47
  const int row0 = (inner & 15) * 128;
  const int ks = inner >> 4;                   // 0..2
  const int jt0 = ks * 11;
  const int jtN = jt0 + ((ks < 2) ? 11 : 10);

  Frag8 qf[2][4];
#pragma unroll
  for (int nb = 0; nb < 2; ++nb) {
    const unsigned short* qp = Qcat + ((size_t)(bh*2048 + row0 + wq*32 + nb*16 + l15))*128 + lq*8;
#pragma unroll
    for (int kst = 0; kst < 4; ++kst)
      qf[nb][kst].v = *(const bf16x8*)(qp + kst*32);
  }

  f32x4 o[4][2];
  float lp[2] = {0.f, 0.f};
#pragma unroll
  for (int db = 0; db < 4; ++db)
#pragma unroll
    for (int nb = 0; nb < 2; ++nb) { f32x4 z = {0.f,0.f,0.f,0.f}; o[db][nb] = z; }

  const unsigned short* kgb = Kcat + ((size_t)bh*2048)*128;
  const unsigned short* vg  = Vt + (size_t)bh*64*2048;

  for (int jt = jt0; jt < jtN; ++jt) {
    __syncthreads();
#pragma unroll
    for (int t = 0; t < 4; ++t) {
      int g = (wq*4 + t)*4 + (lane >> 4);
      int slot = lane & 15;
      int chunk = (slot & 8) | ((slot ^ g) & 7);
      gl_lds16(kgb + (size_t)(jt*64 + g)*128 + chunk*8, Ks + (wq*4 + t)*512);
    }
#pragma unroll
    for (int t = 0; t < 2; ++t) {
      int rv = (wq*2 + t)*8 + (lane >> 3);
      int chunk = (lane & 7) ^ (rv & 7);
      gl_lds16(vg + (size_t)rv*2048 + jt*64 + chunk*8, Vs + (wq*2 + t)*512);
    }
    __syncthreads();

    unsigned P2[2][4][2];
#pragma unroll
    for (int kb = 0; kb < 4; ++kb) {
      bf16x8 af[4];
#pragma unroll
      for (int kst = 0; kst < 4; ++kst) {
        int key = kb*16 + l15;
        int c = kst*4 + lq;
        int slot = (c & 8) | ((c ^ key) & 7);
        af[kst] = *(const bf16x8*)&Ks[key*128 + slot*8];
      }
      f32x4 s[2];
      { f32x4 z = {0.f,0.f,0.f,0.f}; s[0] = z; s[1] = z; }
#pragma unroll
      for (int kst = 0; kst < 4; ++kst) {
        s[0] = __builtin_amdgcn_mfma_f32_16x16x32_bf16(af[kst], qf[0][kst].v, s[0], 0,0,0);
        s[1] = __builtin_amdgcn_mfma_f32_16x16x32_bf16(af[kst], qf[1][kst].v, s[1], 0,0,0);
      }
#pragma unroll
      for (int nb = 0; nb < 2; ++nb) {
        float e0 = __expf(s[nb][0]), e1 = __expf(s[nb][1]);
        float e2 = __expf(s[nb][2]), e3 = __expf(s[nb][3]);
        unsigned pk0 = __builtin_amdgcn_perm(__float_as_uint(e1), __float_as_uint(e0), 0x07060302u);
        unsigned pk1 = __builtin_amdgcn_perm(__float_as_uint(e3), __float_as_uint(e2), 0x07060302u);
        lp[nb] += __uint_as_float(pk0 << 16) + __uint_as_float(pk0 & 0xffff0000u)
                + __uint_as_float(pk1 << 16) + __uint_as_float(pk1 & 0xffff0000u);
        P2[nb][kb][0] = pk0;
        P2[nb][kb][1] = pk1;
      }
    }

    // PV: O^T += V^T . P^T  (B-frags packed in-register; key perm folded
    // into the V^T A-frag b64 reads)
#pragma unroll
    for (int t = 0; t < 2; ++t) {
      FragU bfr[2];
#pragma unroll
      for (int nb = 0; nb < 2; ++nb) {
        bfr[nb].u[0] = P2[nb][2*t][0];
        bfr[nb].u[1] = P2[nb][2*t][1];
        bfr[nb].u[2] = P2[nb][2*t+1][0];
        bfr[nb].u[3] = P2[nb][2*t+1][1];
      }
      const int c0 = 4*t + (lq >> 1);
      const int woff = 4*(lq & 1);
#pragma unroll
      for (int db = 0; db < 4; ++db) {
        int d = db*16 + l15;
        FragQ va;
        va.q[0] = *(const unsigned long long*)&Vs[d*64 + ((c0     ^ (d & 7))*8) + woff];
        va.q[1] = *(const unsigned long long*)&Vs[d*64 + (((c0+2) ^ (d & 7))*8) + woff];
        o[db][0] = __builtin_amdgcn_mfma_f32_16x16x32_bf16(va.v, bfr[0].v, o[db][0], 0,0,0);
        o[db][1] = __builtin_amdgcn_mfma_f32_16x16x32_bf16(va.v, bfr[1].v, o[db][1], 0,0,0);
      }
    }
  }

  // epilogue: explicit per-slice partials
  float* OP = (ks == 0) ? OP0 : (ks == 1) ? OP1 : OP2;
#pragma unroll
  for (int nb = 0; nb < 2; ++nb) {
    float rs = lp[nb];
    rs += __shfl_xor(rs, 16, 64);
    rs += __shfl_xor(rs, 32, 64);
    int qrow = row0 + wq*32 + nb*16 + l15;
    if (lq == 0) lpart[(size_t)ks*65536 + bh*2048 + qrow] = rs;
#pragma unroll
    for (int db = 0; db < 4; ++db)
#pragma unroll
      for (int r = 0; r < 4; ++r) {
        int d = db*16 + lq*4 + r;
        OP[(size_t)(bh*64 + d)*2048 + qrow] = o[db][nb][r];
      }
  }
}

// ---------------------------------------------------------------------------
// combine3: attcat[b,s,h*64+d](hi|lo) = sum_k OPk[bh][d][s] / sum_k lk[bh][s]
// ---------------------------------------------------------------------------
__global__ __launch_bounds__(256) void combine3(const float* __restrict__ OP0,
                                                const float* __restrict__ OP1,
                                                const float* __restrict__ OP2,
                                                const float* __restrict__ lpart,
                                                unsigned short* __restrict__ attcat)
{
  __shared__ float Ts[64*68];
  __shared__ float Ls[64];
  const int tid = threadIdx.x;
  const int bh = blockIdx.y, s0 = blockIdx.x * 64;
  const int b = bh >> 4, h = bh & (NH-1);
#pragma unroll
  for (int c = 0; c < 4; ++c) {
    int fid = tid + c*256;
    int d = fid >> 4, s4 = fid & 15;
    size_t gi = ((size_t)(bh*64 + d))*2048 + s0 + s4*4;
    float4 a = *(const float4*)&OP0[gi];
    float4 bb = *(const float4*)&OP1[gi];
    float4 cc = *(const float4*)&OP2[gi];
    Ts[(s4*4+0)*68 + d] = a.x + bb.x + cc.x;
    Ts[(s4*4+1)*68 + d] = a.y + bb.y + cc.y;
    Ts[(s4*4+2)*68 + d] = a.z + bb.z + cc.z;
    Ts[(s4*4+3)*68 + d] = a.w + bb.w + cc.w;
  }
  if (tid < 64) {
    size_t li = (size_t)bh*2048 + s0 + tid;
    Ls[tid] = lpart[li] + lpart[65536 + li] + lpart[131072 + li];
  }
  __syncthreads();
  const int sl = tid >> 2, d0 = (tid & 3) * 16;
  const float inv = 1.f / Ls[sl];
  const size_t rb = ((size_t)(b*2048 + s0 + sl))*2048 + h*64;
#pragma unroll
  for (int j4 = 0; j4 < 4; ++j4) {
    float4 t = *(const float4*)&Ts[sl*68 + d0 + j4*4];
    float v0 = t.x*inv, v1 = t.y*inv, v2 = t.z*inv, v3 = t.w*inv;
    ushort4 hi, lo;
    hi.x = f2bf(v0); lo.x = f2bf(v0 - bf2f(hi.x));
    hi.y = f2bf(v1); lo.y = f2bf(v1 - bf2f(hi.y));
    hi.z = f2bf(v2); lo.z = f2bf(v2 - bf2f(hi.z));
    hi.w = f2bf(v3); lo.w = f2bf(v3 - bf2f(hi.w));
    *(ushort4*)&attcat[rb + d0 + j4*4]        = hi;
    *(ushort4*)&attcat[rb + 1024 + d0 + j4*4] = lo;
  }
}

// ---------------------------------------------------------------------------
// gemm3: out = attn@Wo^T + bo, split-bf16 3-term.
// ---------------------------------------------------------------------------
__global__ __launch_bounds__(256) void gemm3(const unsigned short* __restrict__ A,
                                             const unsigned short* __restrict__ W,
                                             const float* __restrict__ bias,
                                             float* __restrict__ out)
{
  __shared__ unsigned short S[16384];
  const int tid = threadIdx.x, lane = tid & 63, wq = tid >> 6;
  const int l15 = lane & 15, lq = lane >> 4;
  const int n0 = blockIdx.x * 64, m0 = blockIdx.y * 64;
  const int wr = (wq & 1) * 32, wc = (wq >> 1) * 32;

  f32x4 acc[2][2];
#pragma unroll
  for (int mb = 0; mb < 2; ++mb)
#pragma unroll
    for (int nb = 0; nb < 2; ++nb) { f32x4 z = {0.f,0.f,0.f,0.f}; acc[mb][nb] = z; }

  const unsigned short* mat = (wq < 2) ? A : W;
  const int rbase = (wq < 2) ? m0 : n0;
  const int koffadd = (wq & 1) * 1024;
  unsigned short* lbase = S + wq * 4096;
  const int srow = lane >> 3, sslot = lane & 7;

  for (int k0 = 0; k0 < 1024; k0 += 64) {
    __syncthreads();
#pragma unroll
    for (int t = 0; t < 8; ++t) {
      int row = t*8 + srow;
      int chunk = sslot ^ (row & 7);
      gl_lds16(mat + (size_t)(rbase + row)*2048 + koffadd + k0 + chunk*8, lbase + t*512);
    }
    __syncthreads();
#pragma unroll
    for (int kk = 0; kk < 2; ++kk) {
      int c = kk*4 + lq;
      bf16x8 ah[2], al[2], bh_[2], bl_[2];
#pragma unroll
      for (int mb = 0; mb < 2; ++mb) {
        int m = wr + mb*16 + l15;
        int so = (c ^ (m & 7))*8;
        ah[mb] = *(const bf16x8*)&S[m*64 + so];
        al[mb] = *(const bf16x8*)&S[4096 + m*64 + so];
      }
#pragma unroll
      for (int nb = 0; nb < 2; ++nb) {
        int n = wc + nb*16 + l15;
        int so = (c ^ (n & 7))*8;
        bh_[nb] = *(const bf16x8*)&S[8192  + n*64 + so];
        bl_[nb] = *(const bf16x8*)&S[12288 + n*64 + so];
      }
#pragma unroll
      for (int mb = 0; mb < 2; ++mb)
#pragma unroll
        for (int nb = 0; nb < 2; ++nb) {
          acc[mb][nb] = __builtin_amdgcn_mfma_f32_16x16x32_bf16(ah[mb], bh_[nb], acc[mb][nb], 0,0,0);
          acc[mb][nb] = __builtin_amdgcn_mfma_f32_16x16x32_bf16(al[mb], bh_[nb], acc[mb][nb], 0,0,0);
          acc[mb][nb] = __builtin_amdgcn_mfma_f32_16x16x32_bf16(ah[mb], bl_[nb], acc[mb][nb], 0,0,0);
        }
    }
  }

  float bvv[2];
#pragma unroll
  for (int nb = 0; nb < 2; ++nb) bvv[nb] = bias[n0 + wc + nb*16 + l15];
#pragma unroll
  for (int mb = 0; mb < 2; ++mb)
#pragma unroll
    for (int r = 0; r < 4; ++r) {
      int m = m0 + wr + mb*16 + lq*4 + r;
#pragma unroll
      for (int nb = 0; nb < 2; ++nb) {
        int n = n0 + wc + nb*16 + l15;
        out[(size_t)m*1024 + n] = acc[mb][nb][r] + bvv[nb];
      }
    }
}

// ---------------------------------------------------------------------------
extern "C" void kernel_launch(void* const* d_in, const int* in_sizes, int n_in,
                              void* d_out, int out_size, void* d_ws, size_t ws_size,
                              hipStream_t stream)
{
  const float* x   = (const float*)d_in[0];
  const float* Wq  = (const float*)d_in[1];
  const float* bq  = (const float*)d_in[2];
  const float* Wk  = (const float*)d_in[3];
  const float* bk  = (const float*)d_in[4];
  const float* Wv  = (const float*)d_in[5];
  const float* bv  = (const float*)d_in[6];
  const float* Wo  = (const float*)d_in[7];
  const float* bo  = (const float*)d_in[8];
  const float* J   = (const float*)d_in[9];
  const float* lam = (const float*)d_in[10];

  // ws layout (~114 MB). Region A (xh|wcat3|Jt|pad, 16.9 MB) is dead after
  // build_qj2 and is ALIASED by OPart slice 2 during flash6.
  char* p = (char*)d_ws;
  char* regionA = p;
  unsigned short* xh     = (unsigned short*)p;  p += (size_t)4096*1024*2;    //  8.39M
  unsigned short* wcat3  = (unsigned short*)p;  p += (size_t)3072*1024*2;    //  6.29M
  unsigned short* Jt     = (unsigned short*)p;  p += (size_t)16*64*64*2;     //  0.13M
  p += (size_t)2*1024*1024;                      // pad -> regionA >= 16.78M
  unsigned short* Qcat   = (unsigned short*)p;  p += (size_t)65536*128*2;    // 16.78M
  unsigned short* Kcat   = (unsigned short*)p;  p += (size_t)65536*128*2;    // 16.78M
  unsigned short* Vt     = (unsigned short*)p;  p += (size_t)32*64*2048*2;   //  8.39M
  unsigned short* wocat  = (unsigned short*)p;  p += (size_t)1024*2048*2;    //  4.19M
  unsigned short* attcat = (unsigned short*)p;  p += (size_t)4096*2048*2;    // 16.78M
  float*          OP0    = (float*)p;           p += (size_t)32*64*2048*4;   // 16.78M
  float*          OP1    = (float*)p;           p += (size_t)32*64*2048*4;   // 16.78M
  float*          lpart  = (float*)p;           p += (size_t)3*65536*4;      //  0.79M
  float*          OP2    = (float*)regionA;      // alias over dead region A
  float* out = (float*)d_out;

  dim3 blk(256);

  prep_all<<<dim3(8192), blk, 0, stream>>>(x, Wq, Wk, Wv, Wo, xh, wcat3, wocat);
  prep_jt<<<dim3(16), blk, 0, stream>>>(J, lam, Jt);
  gemm_qkv<<<dim3(24, 32), blk, 0, stream>>>(xh, wcat3, bq, bk, bv, Qcat, Kcat, Vt);
  build_qj2<<<dim3(16, 32), blk, 0, stream>>>(Qcat, Jt);
  flash6<<<dim3(1536), blk, 0, stream>>>(Qcat, Kcat, Vt, OP0, OP1, OP2, lpart);
  combine3<<<dim3(32, 32), blk, 0, stream>>>(OP0, OP1, OP2, lpart, attcat);
  gemm3<<<dim3(16, 64), blk, 0, stream>>>(attcat, wocat, bo, out);
}

// Round 8
// 258.404 us; speedup vs baseline: 1.7808x; 1.7195x over previous
//
#include <hip/hip_runtime.h>
#include <math.h>

#define NH 16

typedef __bf16 bf16x8 __attribute__((ext_vector_type(8)));
typedef float f32x4 __attribute__((ext_vector_type(4)));

__device__ __forceinline__ unsigned short f2bf(float f) {
  unsigned u = __float_as_uint(f);
  u += 0x7fffu + ((u >> 16) & 1u);            // RNE (prep/epilogue paths only)
  return (unsigned short)(u >> 16);
}
__device__ __forceinline__ float bf2f(unsigned short h) {
  return __uint_as_float(((unsigned)h) << 16);
}
__device__ __forceinline__ float fast_tanh16(float x) {
  // tanh(8*x) for x = Q/8: 1 - 2/(e^{16x}+1)
  return 1.f - 2.f / (__expf(16.f * x) + 1.f);
}
__device__ __forceinline__ void gl_lds16(const void* g, void* l) {
  __builtin_amdgcn_global_load_lds((const __attribute__((address_space(1))) void*)g,
                                   (__attribute__((address_space(3))) void*)l, 16, 0, 0);
}
union Frag8 { bf16x8 v; unsigned short u[8]; };
union FragU { bf16x8 v; unsigned u[4]; };
union FragQ { bf16x8 v; unsigned long long q[2]; };

// ---------------------------------------------------------------------------
// prep_all: one launch for all input conversions.
// ---------------------------------------------------------------------------
__global__ __launch_bounds__(256) void prep_all(const float* __restrict__ x,
                                                const float* __restrict__ Wq,
                                                const float* __restrict__ Wk,
                                                const float* __restrict__ Wv,
                                                const float* __restrict__ Wo,
                                                unsigned short* __restrict__ xh,
                                                unsigned short* __restrict__ wcat3,
                                                unsigned short* __restrict__ wocat)
{
  const int bid = blockIdx.x, tid = threadIdx.x;
  if (bid < 4096) {
    int i = bid * 256 + tid;
    float4 v = *(const float4*)&x[(size_t)i*4];
    ushort4 o;
    o.x = f2bf(v.x); o.y = f2bf(v.y); o.z = f2bf(v.z); o.w = f2bf(v.w);
    *(ushort4*)&xh[(size_t)i*4] = o;
  } else if (bid < 7168) {
    int i = (bid - 4096) * 256 + tid;
    int sel = i >> 18, loc = i & 262143;
    const float* src = (sel == 0) ? Wq : (sel == 1) ? Wk : Wv;
    float4 v = *(const float4*)&src[(size_t)loc*4];
    ushort4 o;
    o.x = f2bf(v.x); o.y = f2bf(v.y); o.z = f2bf(v.z); o.w = f2bf(v.w);
    *(ushort4*)&wcat3[(size_t)i*4] = o;
  } else {
    int i = (bid - 7168) * 256 + tid;
    int r = i >> 8, c = i & 255;
    float4 v = *(const float4*)&Wo[(size_t)r*1024 + c*4];
    ushort4 hi, lo;
    hi.x = f2bf(v.x); lo.x = f2bf(v.x - bf2f(hi.x));
    hi.y = f2bf(v.y); lo.y = f2bf(v.y - bf2f(hi.y));
    hi.z = f2bf(v.z); lo.z = f2bf(v.z - bf2f(hi.z));
    hi.w = f2bf(v.w); lo.w = f2bf(v.w - bf2f(hi.w));
    *(ushort4*)&wocat[(size_t)r*2048 + c*4]        = hi;
    *(ushort4*)&wocat[(size_t)r*2048 + 1024 + c*4] = lo;
  }
}

// ---------------------------------------------------------------------------
// prep_jt: Jt[h][e][d] = bf16( lam * J[h][d][e] )
// ---------------------------------------------------------------------------
__global__ __launch_bounds__(256) void prep_jt(const float* __restrict__ J,
                                               const float* __restrict__ lam_p,
                                               unsigned short* __restrict__ Jt)
{
  __shared__ float T[64][65];
  const int h = blockIdx.x, tid = threadIdx.x;
  const float lam = lam_p[0];
#pragma unroll
  for (int c = 0; c < 4; ++c) {
    int i = tid + c*256;
    int d = i >> 4, e4 = i & 15;
    float4 v = *(const float4*)&J[(size_t)h*4096 + d*64 + e4*4];
    T[d][e4*4+0] = v.x; T[d][e4*4+1] = v.y; T[d][e4*4+2] = v.z; T[d][e4*4+3] = v.w;
  }
  __syncthreads();
  const int e = tid >> 2, d0 = (tid & 3) * 16;
#pragma unroll
  for (int j4 = 0; j4 < 4; ++j4) {
    ushort4 o;
    o.x = f2bf(lam * T[d0+j4*4+0][e]);
    o.y = f2bf(lam * T[d0+j4*4+1][e]);
    o.z = f2bf(lam * T[d0+j4*4+2][e]);
    o.w = f2bf(lam * T[d0+j4*4+3][e]);
    *(ushort4*)&Jt[((size_t)h*64 + e)*64 + d0 + j4*4] = o;
  }
}

// ---------------------------------------------------------------------------
// gemm_qkv: merged Q/K/V projection, 1-term bf16, 128x128 tile, BK=64.
// ---------------------------------------------------------------------------
__global__ __launch_bounds__(256) void gemm_qkv(const unsigned short* __restrict__ A,
                                                const unsigned short* __restrict__ W,
                                                const float* __restrict__ bq,
                                                const float* __restrict__ bk,
                                                const float* __restrict__ bv,
                                                unsigned short* __restrict__ Qcat,
                                                unsigned short* __restrict__ Kcat,
                                                unsigned short* __restrict__ Vt)
{
  __shared__ unsigned short S[16384];
  const int tid = threadIdx.x, lane = tid & 63, wq = tid >> 6;
  const int l15 = lane & 15, lq = lane >> 4;
  const int n0 = blockIdx.x * 128, m0 = blockIdx.y * 128;
  const int wr = (wq & 1) * 64, wc = (wq >> 1) * 64;
  const int mode = n0 >> 10;

  f32x4 acc[4][4];
#pragma unroll
  for (int mb = 0; mb < 4; ++mb)
#pragma unroll
    for (int nb = 0; nb < 4; ++nb) { f32x4 z = {0.f,0.f,0.f,0.f}; acc[mb][nb] = z; }

  const unsigned short* mat = (wq < 2) ? A : W;
  const int rbase = (wq < 2) ? m0 : n0;
  unsigned short* lbase = S + (wq >> 1) * 8192;
  const int srow = lane >> 3, sslot = lane & 7;

  for (int k0 = 0; k0 < 1024; k0 += 64) {
    __syncthreads();
#pragma unroll
    for (int t = 0; t < 8; ++t) {
      int row = (wq & 1) * 64 + t*8 + srow;
      int chunk = sslot ^ (row & 7);
      gl_lds16(mat + (size_t)(rbase + row)*1024 + k0 + chunk*8,
               lbase + ((wq & 1) * 64 + t*8) * 64);
    }
    __syncthreads();
#pragma unroll
    for (int kk = 0; kk < 2; ++kk) {
      int c = kk*4 + lq;
      bf16x8 af[4], bf_[4];
#pragma unroll
      for (int mb = 0; mb < 4; ++mb) {
        int m = wr + mb*16 + l15;
        af[mb] = *(const bf16x8*)&S[m*64 + (c ^ (m & 7))*8];
      }
#pragma unroll
      for (int nb = 0; nb < 4; ++nb) {
        int n = wc + nb*16 + l15;
        bf_[nb] = *(const bf16x8*)&S[8192 + n*64 + (c ^ (n & 7))*8];
      }
#pragma unroll
      for (int mb = 0; mb < 4; ++mb)
#pragma unroll
        for (int nb = 0; nb < 4; ++nb)
          acc[mb][nb] = __builtin_amdgcn_mfma_f32_16x16x32_bf16(af[mb], bf_[nb], acc[mb][nb], 0,0,0);
    }
  }

  const float* bias = (mode == 0) ? bq : (mode == 1) ? bk : bv;
  float bvv[4];
#pragma unroll
  for (int nb = 0; nb < 4; ++nb) bvv[nb] = bias[((n0 & 1023) + wc + nb*16 + l15)];

  if (mode == 2) {
#pragma unroll
    for (int mb = 0; mb < 4; ++mb) {
      int mrow = m0 + wr + mb*16 + lq*4;
      int b = mrow >> 11, s0 = mrow & 2047;
#pragma unroll
      for (int nb = 0; nb < 4; ++nb) {
        int n = (n0 & 1023) + wc + nb*16 + l15;
        int h = n >> 6, d = n & 63;
        ushort4 o;
        o.x = f2bf(acc[mb][nb][0] + bvv[nb]);
        o.y = f2bf(acc[mb][nb][1] + bvv[nb]);
        o.z = f2bf(acc[mb][nb][2] + bvv[nb]);
        o.w = f2bf(acc[mb][nb][3] + bvv[nb]);
        *(ushort4*)&Vt[((size_t)(b*NH + h)*64 + d)*2048 + s0] = o;
      }
    }
    return;
  }

#pragma unroll
  for (int mb = 0; mb < 4; ++mb) {
#pragma unroll
    for (int r = 0; r < 4; ++r) {
      int m = m0 + wr + mb*16 + lq*4 + r;
      int b = m >> 11, s = m & 2047;
#pragma unroll
      for (int nb = 0; nb < 4; ++nb) {
        float v = acc[mb][nb][r] + bvv[nb];
        int n = (n0 & 1023) + wc + nb*16 + l15;
        int h = n >> 6, d = n & 63;
        size_t row = ((size_t)(b*NH + h)*2048 + s)*128;
        if (mode == 0) {
          Qcat[row + d] = f2bf(v * 0.125f);
        } else {
          Kcat[row + d]      = f2bf(v);
          Kcat[row + 64 + d] = f2bf(1.f - 2.f / (__expf(2.f*v) + 1.f));
        }
      }
    }
  }
}

// ---------------------------------------------------------------------------
// build_qj2: MFMA. Qcat hi = bf16( sum_d tanh(8*q8[d]) * (lam*J[h][d][e]) )
// ---------------------------------------------------------------------------
__global__ __launch_bounds__(256) void build_qj2(unsigned short* __restrict__ Qcat,
                                                 const unsigned short* __restrict__ Jt)
{
  const int tid = threadIdx.x, lane = tid & 63, wq = tid >> 6;
  const int l15 = lane & 15, lq = lane >> 4;
  const int bh = blockIdx.y, row0 = blockIdx.x * 128;
  const int h = bh & (NH-1);

  bf16x8 jf[4][2];
#pragma unroll
  for (int nb = 0; nb < 4; ++nb)
#pragma unroll
    for (int kst = 0; kst < 2; ++kst)
      jf[nb][kst] = *(const bf16x8*)&Jt[((size_t)h*64 + nb*16 + l15)*64 + kst*32 + lq*8];

  Frag8 af[2][2];
#pragma unroll
  for (int mb = 0; mb < 2; ++mb) {
    const unsigned short* qp = Qcat + ((size_t)(bh*2048 + row0 + wq*32 + mb*16 + l15))*128 + lq*8;
#pragma unroll
    for (int kst = 0; kst < 2; ++kst) {
      Frag8 raw;
      raw.v = *(const bf16x8*)(qp + kst*32);
#pragma unroll
      for (int j = 0; j < 8; ++j) {
        float t = fast_tanh16(bf2f(raw.u[j]));
        af[mb][kst].u[j] = (unsigned short)(__float_as_uint(t) >> 16);  // trunc
      }
    }
  }

  f32x4 acc[2][4];
#pragma unroll
  for (int mb = 0; mb < 2; ++mb)
#pragma unroll
    for (int nb = 0; nb < 4; ++nb) { f32x4 z = {0.f,0.f,0.f,0.f}; acc[mb][nb] = z; }
#pragma unroll
  for (int kst = 0; kst < 2; ++kst)
#pragma unroll
    for (int mb = 0; mb < 2; ++mb)
#pragma unroll
      for (int nb = 0; nb < 4; ++nb)
        acc[mb][nb] = __builtin_amdgcn_mfma_f32_16x16x32_bf16(af[mb][kst].v, jf[nb][kst], acc[mb][nb], 0,0,0);

#pragma unroll
  for (int mb = 0; mb < 2; ++mb)
#pragma unroll
    for (int r = 0; r < 4; ++r) {
      size_t rowb = ((size_t)(bh*2048 + row0 + wq*32 + mb*16 + lq*4 + r))*128 + 64;
#pragma unroll
      for (int nb = 0; nb < 4; ++nb)
        Qcat[rowb + nb*16 + l15] = f2bf(acc[mb][nb][r]);
    }
}

// ---------------------------------------------------------------------------
// flash7: S^T MFMA flash, split-K3, explicit f32 partials. grid 1536.
// __launch_bounds__(256,4): R6/R7 showed (256,6) forces the ~85-reg budget
// and the compiler SPILLS TO SCRATCH (~0.9 GB HBM traffic, 3x slowdown).
// At (256,4) the kernel sits at ~96 regs total -> HW still fits 5 waves/SIMD,
// so grid 1536 gives ~5 blocks/CU resident without spills.
// P2 live range halved: PV issued per kb-pair (live P-regs 16 -> 8).
// ---------------------------------------------------------------------------
__global__ __launch_bounds__(256, 4) void flash7(
    const unsigned short* __restrict__ Qcat, const unsigned short* __restrict__ Kcat,
    const unsigned short* __restrict__ Vt, float* __restrict__ OP0,
    float* __restrict__ OP1, float* __restrict__ OP2, float* __restrict__ lpart)
{
  __shared__ unsigned short Ks[64*128];
  __shared__ unsigned short Vs[64*64];
  const int tid = threadIdx.x, lane = tid & 63, wq = tid >> 6;
  const int l15 = lane & 15, lq = lane >> 4;
  const int bid = blockIdx.x;
  // bid = xcd + 8*(bhi + 4*inner): same bh -> same XCD L2
  const int bh = (((bid >> 3) & 3) << 3) | (bid & 7);
  const int inner = bid >> 5;                  // 0..47
  const int row0 = (inner & 15) * 128;
  const int ks = inner >> 4;                   // 0..2
  const int jt0 = ks * 11;
  const int jtN = jt0 + ((ks < 2) ? 11 : 10);

  Frag8 qf[2][4];
#pragma unroll
  for (int nb = 0; nb < 2; ++nb) {
    const unsigned short* qp = Qcat + ((size_t)(bh*2048 + row0 + wq*32 + nb*16 + l15))*128 + lq*8;
#pragma unroll
    for (int kst = 0; kst < 4; ++kst)
      qf[nb][kst].v = *(const bf16x8*)(qp + kst*32);
  }

  f32x4 o[4][2];
  float lp[2] = {0.f, 0.f};
#pragma unroll
  for (int db = 0; db < 4; ++db)
#pragma unroll
    for (int nb = 0; nb < 2; ++nb) { f32x4 z = {0.f,0.f,0.f,0.f}; o[db][nb] = z; }

  const unsigned short* kgb = Kcat + ((size_t)bh*2048)*128;
  const unsigned short* vg  = Vt + (size_t)bh*64*2048;

  for (int jt = jt0; jt < jtN; ++jt) {
    __syncthreads();
#pragma unroll
    for (int t = 0; t < 4; ++t) {
      int g = (wq*4 + t)*4 + (lane >> 4);
      int slot = lane & 15;
      int chunk = (slot & 8) | ((slot ^ g) & 7);
      gl_lds16(kgb + (size_t)(jt*64 + g)*128 + chunk*8, Ks + (wq*4 + t)*512);
    }
#pragma unroll
    for (int t = 0; t < 2; ++t) {
      int rv = (wq*2 + t)*8 + (lane >> 3);
      int chunk = (lane & 7) ^ (rv & 7);
      gl_lds16(vg + (size_t)rv*2048 + jt*64 + chunk*8, Vs + (wq*2 + t)*512);
    }
    __syncthreads();

    // process keys in two half-tiles of 32: QK^T + exp then immediately PV,
    // so only 8 packed-P regs are live at a time.
#pragma unroll
    for (int t = 0; t < 2; ++t) {
      unsigned P2[2][2][2];
#pragma unroll
      for (int kk = 0; kk < 2; ++kk) {
        const int kb = 2*t + kk;
        bf16x8 af[4];
#pragma unroll
        for (int kst = 0; kst < 4; ++kst) {
          int key = kb*16 + l15;
          int c = kst*4 + lq;
          int slot = (c & 8) | ((c ^ key) & 7);
          af[kst] = *(const bf16x8*)&Ks[key*128 + slot*8];
        }
        f32x4 s[2];
        { f32x4 z = {0.f,0.f,0.f,0.f}; s[0] = z; s[1] = z; }
#pragma unroll
        for (int kst = 0; kst < 4; ++kst) {
          s[0] = __builtin_amdgcn_mfma_f32_16x16x32_bf16(af[kst], qf[0][kst].v, s[0], 0,0,0);
          s[1] = __builtin_amdgcn_mfma_f32_16x16x32_bf16(af[kst], qf[1][kst].v, s[1], 0,0,0);
        }
#pragma unroll
        for (int nb = 0; nb < 2; ++nb) {
          float e0 = __expf(s[nb][0]), e1 = __expf(s[nb][1]);
          float e2 = __expf(s[nb][2]), e3 = __expf(s[nb][3]);
          unsigned pk0 = __builtin_amdgcn_perm(__float_as_uint(e1), __float_as_uint(e0), 0x07060302u);
          unsigned pk1 = __builtin_amdgcn_perm(__float_as_uint(e3), __float_as_uint(e2), 0x07060302u);
          lp[nb] += __uint_as_float(pk0 << 16) + __uint_as_float(pk0 & 0xffff0000u)
                  + __uint_as_float(pk1 << 16) + __uint_as_float(pk1 & 0xffff0000u);
          P2[nb][kk][0] = pk0;
          P2[nb][kk][1] = pk1;
        }
      }

      // PV for this half-tile (keys t*32 .. t*32+31)
      FragU bfr[2];
#pragma unroll
      for (int nb = 0; nb < 2; ++nb) {
        bfr[nb].u[0] = P2[nb][0][0];
        bfr[nb].u[1] = P2[nb][0][1];
        bfr[nb].u[2] = P2[nb][1][0];
        bfr[nb].u[3] = P2[nb][1][1];
      }
      const int c0 = 4*t + (lq >> 1);
      const int woff = 4*(lq & 1);
#pragma unroll
      for (int db = 0; db < 4; ++db) {
        int d = db*16 + l15;
        FragQ va;
        va.q[0] = *(const unsigned long long*)&Vs[d*64 + ((c0     ^ (d & 7))*8) + woff];
        va.q[1] = *(const unsigned long long*)&Vs[d*64 + (((c0+2) ^ (d & 7))*8) + woff];
        o[db][0] = __builtin_amdgcn_mfma_f32_16x16x32_bf16(va.v, bfr[0].v, o[db][0], 0,0,0);
        o[db][1] = __builtin_amdgcn_mfma_f32_16x16x32_bf16(va.v, bfr[1].v, o[db][1], 0,0,0);
      }
    }
  }

  // epilogue: explicit per-slice partials
  float* OP = (ks == 0) ? OP0 : (ks == 1) ? OP1 : OP2;
#pragma unroll
  for (int nb = 0; nb < 2; ++nb) {
    float rs = lp[nb];
    rs += __shfl_xor(rs, 16, 64);
    rs += __shfl_xor(rs, 32, 64);
    int qrow = row0 + wq*32 + nb*16 + l15;
    if (lq == 0) lpart[(size_t)ks*65536 + bh*2048 + qrow] = rs;
#pragma unroll
    for (int db = 0; db < 4; ++db)
#pragma unroll
      for (int r = 0; r < 4; ++r) {
        int d = db*16 + lq*4 + r;
        OP[(size_t)(bh*64 + d)*2048 + qrow] = o[db][nb][r];
      }
  }
}

// ---------------------------------------------------------------------------
// combine3: attcat[b,s,h*64+d](hi|lo) = sum_k OPk[bh][d][s] / sum_k lk[bh][s]
// ---------------------------------------------------------------------------
__global__ __launch_bounds__(256) void combine3(const float* __restrict__ OP0,
                                                const float* __restrict__ OP1,
                                                const float* __restrict__ OP2,
                                                const float* __restrict__ lpart,
                                                unsigned short* __restrict__ attcat)
{
  __shared__ float Ts[64*68];
  __shared__ float Ls[64];
  const int tid = threadIdx.x;
  const int bh = blockIdx.y, s0 = blockIdx.x * 64;
  const int b = bh >> 4, h = bh & (NH-1);
#pragma unroll
  for (int c = 0; c < 4; ++c) {
    int fid = tid + c*256;
    int d = fid >> 4, s4 = fid & 15;
    size_t gi = ((size_t)(bh*64 + d))*2048 + s0 + s4*4;
    float4 a = *(const float4*)&OP0[gi];
    float4 bb = *(const float4*)&OP1[gi];
    float4 cc = *(const float4*)&OP2[gi];
    Ts[(s4*4+0)*68 + d] = a.x + bb.x + cc.x;
    Ts[(s4*4+1)*68 + d] = a.y + bb.y + cc.y;
    Ts[(s4*4+2)*68 + d] = a.z + bb.z + cc.z;
    Ts[(s4*4+3)*68 + d] = a.w + bb.w + cc.w;
  }
  if (tid < 64) {
    size_t li = (size_t)bh*2048 + s0 + tid;
    Ls[tid] = lpart[li] + lpart[65536 + li] + lpart[131072 + li];
  }
  __syncthreads();
  const int sl = tid >> 2, d0 = (tid & 3) * 16;
  const float inv = 1.f / Ls[sl];
  const size_t rb = ((size_t)(b*2048 + s0 + sl))*2048 + h*64;
#pragma unroll
  for (int j4 = 0; j4 < 4; ++j4) {
    float4 t = *(const float4*)&Ts[sl*68 + d0 + j4*4];
    float v0 = t.x*inv, v1 = t.y*inv, v2 = t.z*inv, v3 = t.w*inv;
    ushort4 hi, lo;
    hi.x = f2bf(v0); lo.x = f2bf(v0 - bf2f(hi.x));
    hi.y = f2bf(v1); lo.y = f2bf(v1 - bf2f(hi.y));
    hi.z = f2bf(v2); lo.z = f2bf(v2 - bf2f(hi.z));
    hi.w = f2bf(v3); lo.w = f2bf(v3 - bf2f(hi.w));
    *(ushort4*)&attcat[rb + d0 + j4*4]        = hi;
    *(ushort4*)&attcat[rb + 1024 + d0 + j4*4] = lo;
  }
}

// ---------------------------------------------------------------------------
// gemm3: out = attn@Wo^T + bo, split-bf16 3-term.
// ---------------------------------------------------------------------------
__global__ __launch_bounds__(256) void gemm3(const unsigned short* __restrict__ A,
                                             const unsigned short* __restrict__ W,
                                             const float* __restrict__ bias,
                                             float* __restrict__ out)
{
  __shared__ unsigned short S[16384];
  const int tid = threadIdx.x, lane = tid & 63, wq = tid >> 6;
  const int l15 = lane & 15, lq = lane >> 4;
  const int n0 = blockIdx.x * 64, m0 = blockIdx.y * 64;
  const int wr = (wq & 1) * 32, wc = (wq >> 1) * 32;

  f32x4 acc[2][2];
#pragma unroll
  for (int mb = 0; mb < 2; ++mb)
#pragma unroll
    for (int nb = 0; nb < 2; ++nb) { f32x4 z = {0.f,0.f,0.f,0.f}; acc[mb][nb] = z; }

  const unsigned short* mat = (wq < 2) ? A : W;
  const int rbase = (wq < 2) ? m0 : n0;
  const int koffadd = (wq & 1) * 1024;
  unsigned short* lbase = S + wq * 4096;
  const int srow = lane >> 3, sslot = lane & 7;

  for (int k0 = 0; k0 < 1024; k0 += 64) {
    __syncthreads();
#pragma unroll
    for (int t = 0; t < 8; ++t) {
      int row = t*8 + srow;
      int chunk = sslot ^ (row & 7);
      gl_lds16(mat + (size_t)(rbase + row)*2048 + koffadd + k0 + chunk*8, lbase + t*512);
    }
    __syncthreads();
#pragma unroll
    for (int kk = 0; kk < 2; ++kk) {
      int c = kk*4 + lq;
      bf16x8 ah[2], al[2], bh_[2], bl_[2];
#pragma unroll
      for (int mb = 0; mb < 2; ++mb) {
        int m = wr + mb*16 + l15;
        int so = (c ^ (m & 7))*8;
        ah[mb] = *(const bf16x8*)&S[m*64 + so];
        al[mb] = *(const bf16x8*)&S[4096 + m*64 + so];
      }
#pragma unroll
      for (int nb = 0; nb < 2; ++nb) {
        int n = wc + nb*16 + l15;
        int so = (c ^ (n & 7))*8;
        bh_[nb] = *(const bf16x8*)&S[8192  + n*64 + so];
        bl_[nb] = *(const bf16x8*)&S[12288 + n*64 + so];
      }
#pragma unroll
      for (int mb = 0; mb < 2; ++mb)
#pragma unroll
        for (int nb = 0; nb < 2; ++nb) {
          acc[mb][nb] = __builtin_amdgcn_mfma_f32_16x16x32_bf16(ah[mb], bh_[nb], acc[mb][nb], 0,0,0);
          acc[mb][nb] = __builtin_amdgcn_mfma_f32_16x16x32_bf16(al[mb], bh_[nb], acc[mb][nb], 0,0,0);
          acc[mb][nb] = __builtin_amdgcn_mfma_f32_16x16x32_bf16(ah[mb], bl_[nb], acc[mb][nb], 0,0,0);
        }
    }
  }

  float bvv[2];
#pragma unroll
  for (int nb = 0; nb < 2; ++nb) bvv[nb] = bias[n0 + wc + nb*16 + l15];
#pragma unroll
  for (int mb = 0; mb < 2; ++mb)
#pragma unroll
    for (int r = 0; r < 4; ++r) {
      int m = m0 + wr + mb*16 + lq*4 + r;
#pragma unroll
      for (int nb = 0; nb < 2; ++nb) {
        int n = n0 + wc + nb*16 + l15;
        out[(size_t)m*1024 + n] = acc[mb][nb][r] + bvv[nb];
      }
    }
}

// ---------------------------------------------------------------------------
extern "C" void kernel_launch(void* const* d_in, const int* in_sizes, int n_in,
                              void* d_out, int out_size, void* d_ws, size_t ws_size,
                              hipStream_t stream)
{
  const float* x   = (const float*)d_in[0];
  const float* Wq  = (const float*)d_in[1];
  const float* bq  = (const float*)d_in[2];
  const float* Wk  = (const float*)d_in[3];
  const float* bk  = (const float*)d_in[4];
  const float* Wv  = (const float*)d_in[5];
  const float* bv  = (const float*)d_in[6];
  const float* Wo  = (const float*)d_in[7];
  const float* bo  = (const float*)d_in[8];
  const float* J   = (const float*)d_in[9];
  const float* lam = (const float*)d_in[10];

  // ws layout (~114 MB). Region A (xh|wcat3|Jt|pad, 16.9 MB) is dead after
  // build_qj2 and is ALIASED by OPart slice 2 during flash7.
  char* p = (char*)d_ws;
  char* regionA = p;
  unsigned short* xh     = (unsigned short*)p;  p += (size_t)4096*1024*2;    //  8.39M
  unsigned short* wcat3  = (unsigned short*)p;  p += (size_t)3072*1024*2;    //  6.29M
  unsigned short* Jt     = (unsigned short*)p;  p += (size_t)16*64*64*2;     //  0.13M
  p += (size_t)2*1024*1024;                      // pad -> regionA >= 16.78M
  unsigned short* Qcat   = (unsigned short*)p;  p += (size_t)65536*128*2;    // 16.78M
  unsigned short* Kcat   = (unsigned short*)p;  p += (size_t)65536*128*2;    // 16.78M
  unsigned short* Vt     = (unsigned short*)p;  p += (size_t)32*64*2048*2;   //  8.39M
  unsigned short* wocat  = (unsigned short*)p;  p += (size_t)1024*2048*2;    //  4.19M
  unsigned short* attcat = (unsigned short*)p;  p += (size_t)4096*2048*2;    // 16.78M
  float*          OP0    = (float*)p;           p += (size_t)32*64*2048*4;   // 16.78M
  float*          OP1    = (float*)p;           p += (size_t)32*64*2048*4;   // 16.78M
  float*          lpart  = (float*)p;           p += (size_t)3*65536*4;      //  0.79M
  float*          OP2    = (float*)regionA;      // alias over dead region A
  float* out = (float*)d_out;

  dim3 blk(256);

  prep_all<<<dim3(8192), blk, 0, stream>>>(x, Wq, Wk, Wv, Wo, xh, wcat3, wocat);
  prep_jt<<<dim3(16), blk, 0, stream>>>(J, lam, Jt);
  gemm_qkv<<<dim3(24, 32), blk, 0, stream>>>(xh, wcat3, bq, bk, bv, Qcat, Kcat, Vt);
  build_qj2<<<dim3(16, 32), blk, 0, stream>>>(Qcat, Jt);
  flash7<<<dim3(1536), blk, 0, stream>>>(Qcat, Kcat, Vt, OP0, OP1, OP2, lpart);
  combine3<<<dim3(32, 32), blk, 0, stream>>>(OP0, OP1, OP2, lpart, attcat);
  gemm3<<<dim3(16, 64), blk, 0, stream>>>(attcat, wocat, bo, out);
}